// Round 6
// baseline (608.679 us; speedup 1.0000x reference)
//
#include <hip/hip_runtime.h>
#include <math.h>

typedef _Float16 v8h __attribute__((ext_vector_type(8)));
typedef float v4f __attribute__((ext_vector_type(4)));
typedef float v16f __attribute__((ext_vector_type(16)));

// ---------------------------------------------------------------- convert
// NCHW f32 [4,256,56,200] -> NHWC f16 [4,56,200,256]
__global__ void __launch_bounds__(256) convert_kernel(const float* __restrict__ in,
                                                      _Float16* __restrict__ out) {
  const int cb = blockIdx.x * 64, h = blockIdx.y, n = blockIdx.z;
  __shared__ _Float16 tile[64][202];
  const int tid = threadIdx.x;
#pragma unroll 1
  for (int it = 0; it < 50; ++it) {
    int idx = it * 256 + tid;
    int c = idx / 200, w = idx - c * 200;
    tile[c][w] = (_Float16)in[(((size_t)n * 256 + cb + c) * 56 + h) * 200 + w];
  }
  __syncthreads();
#pragma unroll 1
  for (int it = 0; it < 50; ++it) {
    int idx = it * 256 + tid;
    int w = idx >> 6, c = idx & 63;
    out[(((size_t)n * 56 + h) * 200 + w) * 256 + cb + c] = tile[c][w];
  }
}

// ---------------------------------------------------------------- merged weight repack
// conv weights -> [c16-chunk][tap 9][khalf 2][cout 128][part 8] f16 (per conv)
__global__ void __launch_bounds__(256) repack_all_kernel(
    const float* __restrict__ rc_w, const float* __restrict__ bb_w1,
    const float* __restrict__ bb_w2, const float* __restrict__ dp_w,
    _Float16* __restrict__ wrc, _Float16* __restrict__ wbb,
    _Float16* __restrict__ wdp) {
  const int RC = 128 * 256 * 9;
  const int BB = 128 * 128 * 9;
  int i = blockIdx.x * 256 + threadIdx.x;
  if (i < RC) {
    int tap = i % 9, r = i / 9;
    int ci = r % 256, co = r / 256;
    int c = ci >> 4, kh = (ci >> 3) & 1, part = ci & 7;
    wrc[((((size_t)c * 9 + tap) * 2 + kh) * 128 + co) * 8 + part] = (_Float16)rc_w[i];
  } else if (i < RC + 6 * BB) {
    int j = i - RC;
    int blk = j / BB, k = j - blk * BB;
    int tap = k % 9, r = k / 9;
    int ci = r % 128, co = r / 128;
    const float* src = (blk < 3) ? (bb_w1 + (size_t)blk * BB) : (bb_w2 + (size_t)(blk - 3) * BB);
    int slot = (blk < 3) ? (2 * blk) : (2 * (blk - 3) + 1);
    int c = ci >> 4, kh = (ci >> 3) & 1, part = ci & 7;
    wbb[(size_t)slot * BB + ((((size_t)c * 9 + tap) * 2 + kh) * 128 + co) * 8 + part] =
        (_Float16)src[k];
  } else if (i < RC + 6 * BB + 112 * 128) {
    int j = i - RC - 6 * BB;
    wdp[j] = (_Float16)dp_w[j];
  }
}

// ---------------------------------------------------------------- tiny MLP + SE
__global__ void __launch_bounds__(128) mlp_kernel(
    const float* __restrict__ sps, const float* __restrict__ fc1_w,
    const float* __restrict__ fc1_b, const float* __restrict__ fc2_w,
    const float* __restrict__ fc2_b, const float* __restrict__ se_rw,
    const float* __restrict__ se_rb, const float* __restrict__ se_ew,
    const float* __restrict__ se_eb, float* __restrict__ sig) {
  __shared__ float buf[128];
  const int j = threadIdx.x;
  for (int b = 0; b < 4; ++b) {
    float h1 = fmaxf(sps[b] * fc1_w[j] + fc1_b[j], 0.f);
    __syncthreads();
    buf[j] = h1;
    __syncthreads();
    float hm = fc2_b[j];
    for (int k = 0; k < 128; ++k) hm += buf[k] * fc2_w[j * 128 + k];
    __syncthreads();
    buf[j] = hm;
    __syncthreads();
    float t = se_rb[j];
    for (int k = 0; k < 128; ++k) t += buf[k] * se_rw[j * 128 + k];
    t = fmaxf(t, 0.f);
    __syncthreads();
    buf[j] = t;
    __syncthreads();
    float se = se_eb[j];
    for (int k = 0; k < 128; ++k) se += buf[k] * se_ew[j * 128 + k];
    sig[b * 128 + j] = 1.f / (1.f + expf(-se));
  }
}

// ---------------------------------------------------------------- 3x3 conv, implicit GEMM, 32x32x16 f16 MFMA
// Block: 8h x 32w x 128cout (grid 7x7x4 = 196 <= 256 CUs: single pass, no
// multi-block serialization). Wave = M64 (2h x 32w) x N128: each B fragment
// loaded from L2 serves 2 MFMAs (R4 profiling showed per-wave B-refetch from
// L2 was the binding throughput term; M64 halves it).
// A: VGPR-prefetch double-buffered LDS (R4-proven latency hiding; coalesced
// 64B-contiguous global reads) in R5's conflict-free [part 4][pos 340]x16B
// layout. One barrier per 32-ch chunk; 1152 matrix-cy/wave/chunk hides the
// next chunk's A prefetch and this chunk's B loads.
// MODE 0: out = relu((conv + bias)*s + t) * sig_se          (rc conv)
// MODE 1: out = relu(conv*s + t)                            (bb conv1)
// MODE 2: out = relu(xprev + conv*s + t)                    (bb conv2 + residual)
template <int CIN, int MODE>
__global__ void __launch_bounds__(256, 1) conv3x3_kernel(
    const _Float16* __restrict__ act, const _Float16* __restrict__ wr,
    const _Float16* __restrict__ xprev, const float* __restrict__ bias,
    const float* __restrict__ sc, const float* __restrict__ tr,
    const float* __restrict__ sig_se, _Float16* __restrict__ out) {
  const int wt = blockIdx.x, ht = blockIdx.y, n = blockIdx.z;
  const int h0 = ht * 8, w0 = wt * 32;
  const int tid = threadIdx.x;
  const int wave = tid >> 6, lane = tid & 63;
  const int l31 = lane & 31, khalf = lane >> 5;

  // halo 10h x 34w, 32 channels as 4 parts of 8: [part 4][pos 340] x 16B
  __shared__ alignas(16) _Float16 lds[2][4 * 340 * 8];

  // staging map: 1360 v8h slots over 6 rounds of 256 threads
  size_t goff[6];
  int loff[6];
  bool exist[6], ok[6];
#pragma unroll
  for (int it = 0; it < 6; ++it) {
    int slot = it * 256 + tid;
    int pos = slot >> 2, part = slot & 3;  // 4 lanes = 64B contiguous global
    int hh = pos / 34, ww = pos - hh * 34;
    int gh = h0 - 1 + hh, gw = w0 - 1 + ww;
    exist[it] = slot < 1360;
    bool inimg = (unsigned)gh < 56u && (unsigned)gw < 200u;
    ok[it] = exist[it] && inimg;
    loff[it] = (part * 340 + pos) * 8;
    int ghc = ok[it] ? gh : 0, gwc = ok[it] ? gw : 0;
    goff[it] = (((size_t)n * 56 + ghc) * 200 + gwc) * CIN + part * 8;
  }

  const v8h zero8 = {(_Float16)0, (_Float16)0, (_Float16)0, (_Float16)0,
                     (_Float16)0, (_Float16)0, (_Float16)0, (_Float16)0};
  v8h pre[6];
#pragma unroll
  for (int it = 0; it < 6; ++it) pre[it] = ok[it] ? *(const v8h*)(act + goff[it]) : zero8;

  v16f acc[2][4];
#pragma unroll
  for (int mt = 0; mt < 2; ++mt)
#pragma unroll
    for (int nt = 0; nt < 4; ++nt)
#pragma unroll
      for (int r = 0; r < 16; ++r) acc[mt][nt][r] = 0.f;

#pragma unroll 1
  for (int c0 = 0; c0 < CIN; c0 += 32) {
    _Float16* ldsb = &lds[(c0 >> 5) & 1][0];
    // commit prefetched chunk
#pragma unroll
    for (int it = 0; it < 6; ++it)
      if (exist[it]) *(v8h*)(ldsb + loff[it]) = pre[it];
    __syncthreads();
    // prefetch next chunk (hidden behind the MFMA block)
    if (c0 + 32 < CIN) {
#pragma unroll
      for (int it = 0; it < 6; ++it)
        pre[it] = ok[it] ? *(const v8h*)(act + goff[it] + c0 + 32) : zero8;
    }
#pragma unroll
    for (int kkc = 0; kkc < 2; ++kkc) {  // two 16-ch K-slices of the chunk
      const int c16 = (c0 >> 4) + kkc;
      const int apart = kkc * 2 + khalf;
#pragma unroll
      for (int dy = 0; dy < 3; ++dy) {
#pragma unroll
        for (int dx = 0; dx < 3; ++dx) {
          const int tap = dy * 3 + dx;
          const _Float16* wp =
              wr + ((((size_t)c16 * 9 + tap) * 2 + khalf) * 128 + l31) * 8;
          v8h bfrag[4];
#pragma unroll
          for (int nt = 0; nt < 4; ++nt) bfrag[nt] = *(const v8h*)(wp + nt * 32 * 8);
#pragma unroll
          for (int mt = 0; mt < 2; ++mt) {
            const int pos = (wave * 2 + mt + dy) * 34 + l31 + dx;
            v8h afrag = *(const v8h*)(ldsb + (apart * 340 + pos) * 8);
#pragma unroll
            for (int nt = 0; nt < 4; ++nt)
              acc[mt][nt] =
                  __builtin_amdgcn_mfma_f32_32x32x16_f16(afrag, bfrag[nt], acc[mt][nt], 0, 0, 0);
          }
        }
      }
    }
  }

  // epilogue: D layout col(N=cout)=l31, row(M=w-offset)=(r&3)+8*(r>>2)+4*khalf
#pragma unroll
  for (int mt = 0; mt < 2; ++mt) {
    const int h = h0 + wave * 2 + mt;
#pragma unroll
    for (int nt = 0; nt < 4; ++nt) {
      const int cc = nt * 32 + l31;
      const float s = sc[cc], t = tr[cc];
      float bb = 0.f, sg = 1.f;
      if constexpr (MODE == 0) {
        bb = bias[cc];
        sg = sig_se[n * 128 + cc];
      }
#pragma unroll
      for (int r = 0; r < 16; ++r) {
        const int m = (r & 3) + 8 * (r >> 2) + 4 * khalf;
        const int w = w0 + m;
        if (w < 200) {
          float v = acc[mt][nt][r];
          size_t oidx = (((size_t)n * 56 + h) * 200 + w) * 128 + cc;
          if constexpr (MODE == 0) v = fmaxf((v + bb) * s + t, 0.f) * sg;
          if constexpr (MODE == 1) v = fmaxf(v * s + t, 0.f);
          if constexpr (MODE == 2) v = fmaxf((float)xprev[oidx] + v * s + t, 0.f);
          out[oidx] = (_Float16)v;
        }
      }
    }
  }
}

// ---------------------------------------------------------------- depth proj (MFMA) + fused softmax
// x: [44800][128] f16; wdp: [112][128] f16; dp_b: [112] f32
// depth out: f16 [pos][112] (z-contiguous for gridsample)
__global__ void __launch_bounds__(256) depth_proj_softmax_kernel(
    const _Float16* __restrict__ x, const _Float16* __restrict__ wdp,
    const float* __restrict__ dp_b, _Float16* __restrict__ depth) {
  const int wave = threadIdx.x >> 6, lane = threadIdx.x & 63;
  const int q = lane >> 4, l16 = lane & 15;
  const int pos0 = blockIdx.x * 64 + wave * 16;

  v4f acc[7];
#pragma unroll
  for (int nt = 0; nt < 7; ++nt) {
    float bv = dp_b[nt * 16 + l16];
    acc[nt] = {bv, bv, bv, bv};
  }
#pragma unroll
  for (int c0 = 0; c0 < 128; c0 += 32) {
    v8h a = *(const v8h*)(x + (size_t)(pos0 + l16) * 128 + c0 + q * 8);
#pragma unroll
    for (int nt = 0; nt < 7; ++nt) {
      v8h b = *(const v8h*)(wdp + (size_t)(nt * 16 + l16) * 128 + c0 + q * 8);
      acc[nt] = __builtin_amdgcn_mfma_f32_16x16x32_f16(a, b, acc[nt], 0, 0, 0);
    }
  }
  float m[4];
#pragma unroll
  for (int r = 0; r < 4; ++r) {
    m[r] = acc[0][r];
#pragma unroll
    for (int nt = 1; nt < 7; ++nt) m[r] = fmaxf(m[r], acc[nt][r]);
  }
#pragma unroll
  for (int off = 1; off < 16; off <<= 1)
#pragma unroll
    for (int r = 0; r < 4; ++r) m[r] = fmaxf(m[r], __shfl_xor(m[r], off));
  float s[4] = {0.f, 0.f, 0.f, 0.f};
#pragma unroll
  for (int nt = 0; nt < 7; ++nt)
#pragma unroll
    for (int r = 0; r < 4; ++r) {
      float e = expf(acc[nt][r] - m[r]);
      acc[nt][r] = e;
      s[r] += e;
    }
#pragma unroll
  for (int off = 1; off < 16; off <<= 1)
#pragma unroll
    for (int r = 0; r < 4; ++r) s[r] += __shfl_xor(s[r], off);
#pragma unroll
  for (int r = 0; r < 4; ++r) {
    const float inv = 1.f / s[r];
    const size_t p = pos0 + q * 4 + r;
#pragma unroll
    for (int nt = 0; nt < 7; ++nt)
      depth[p * 112 + nt * 16 + l16] = (_Float16)(acc[nt][r] * inv);
  }
}

// ---------------------------------------------------------------- trilinear grid sample (C=1)
__global__ void __launch_bounds__(256) gridsample_kernel(
    const float* __restrict__ grids, const _Float16* __restrict__ depth,
    float* __restrict__ out) {
  const int i = blockIdx.x * 256 + threadIdx.x;
  const int n = i >> 18;
  const float gx = grids[(size_t)i * 3];
  const float gy = grids[(size_t)i * 3 + 1];
  const float gz = grids[(size_t)i * 3 + 2];
  const float ix = (gx + 1.f) * 100.f - 0.5f;
  const float iy = (gy + 1.f) * 28.f - 0.5f;
  const float iz = (gz + 1.f) * 56.f - 0.5f;
  const float xf = floorf(ix), yf = floorf(iy), zf = floorf(iz);
  const int x0 = (int)xf, y0 = (int)yf, z0 = (int)zf;
  const float fx = ix - xf, fy = iy - yf, fz = iz - zf;
  const bool zv0 = (unsigned)z0 < 112u;
  const bool zv1 = (unsigned)(z0 + 1) < 112u;
  const float wz0 = 1.f - fz, wz1 = fz;
  float acc = 0.f;
#pragma unroll
  for (int dy = 0; dy < 2; ++dy) {
    const int yi = y0 + dy;
    const float wy = dy ? fy : 1.f - fy;
#pragma unroll
    for (int dx = 0; dx < 2; ++dx) {
      const int xi = x0 + dx;
      const float wx = dx ? fx : 1.f - fx;
      if ((unsigned)xi < 200u && (unsigned)yi < 56u) {
        const _Float16* bp = depth + ((size_t)n * 11200 + yi * 200 + xi) * 112;
        float v0 = zv0 ? (float)bp[z0] : 0.f;
        float v1 = zv1 ? (float)bp[z0 + 1] : 0.f;
        acc += (wx * wy) * (wz0 * v0 + wz1 * v1);
      }
    }
  }
  out[i] = acc;
}

// ---------------------------------------------------------------- launch
extern "C" void kernel_launch(void* const* d_in, const int* in_sizes, int n_in,
                              void* d_out, int out_size, void* d_ws, size_t ws_size,
                              hipStream_t stream) {
  (void)in_sizes; (void)n_in; (void)out_size; (void)ws_size;
  const float* img = (const float*)d_in[0];
  const float* sps = (const float*)d_in[1];
  const float* grids = (const float*)d_in[2];
  const float* rc_w = (const float*)d_in[3];
  const float* rc_b = (const float*)d_in[4];
  const float* rc_s = (const float*)d_in[5];
  const float* rc_t = (const float*)d_in[6];
  const float* fc1_w = (const float*)d_in[7];
  const float* fc1_b = (const float*)d_in[8];
  const float* fc2_w = (const float*)d_in[9];
  const float* fc2_b = (const float*)d_in[10];
  const float* se_rw = (const float*)d_in[11];
  const float* se_rb = (const float*)d_in[12];
  const float* se_ew = (const float*)d_in[13];
  const float* se_eb = (const float*)d_in[14];
  const float* bb_w1 = (const float*)d_in[15];
  const float* bb_s1 = (const float*)d_in[16];
  const float* bb_t1 = (const float*)d_in[17];
  const float* bb_w2 = (const float*)d_in[18];
  const float* bb_s2 = (const float*)d_in[19];
  const float* bb_t2 = (const float*)d_in[20];
  const float* dp_w = (const float*)d_in[21];
  const float* dp_b = (const float*)d_in[22];
  float* outp = (float*)d_out;

  char* ws = (char*)d_ws;
  _Float16* act16 = (_Float16*)(ws + 0);
  _Float16* depth16 = (_Float16*)(ws + 0);  // reuses act16 slot (act16 dead post rc-conv)
  _Float16* xa = (_Float16*)(ws + 23068672);
  _Float16* xb = (_Float16*)(ws + 23068672 + 11534336);
  _Float16* yb = (_Float16*)(ws + 23068672 + 2 * 11534336);
  _Float16* wrc = (_Float16*)(ws + 57671680);           // 589,824 B
  _Float16* wdp = (_Float16*)(ws + 57671680 + 589824);  // 28,672 B
  _Float16* wbb = (_Float16*)(ws + 58327040);           // 1,769,472 B
  float* sig = (float*)(ws + 58327040 + 1769472);       // 2,048 B

  repack_all_kernel<<<dim3(4664), 256, 0, stream>>>(rc_w, bb_w1, bb_w2, dp_w, wrc, wbb, wdp);
  mlp_kernel<<<1, 128, 0, stream>>>(sps, fc1_w, fc1_b, fc2_w, fc2_b, se_rw, se_rb,
                                    se_ew, se_eb, sig);
  convert_kernel<<<dim3(4, 56, 4), 256, 0, stream>>>(img, act16);

  dim3 cgrid(7, 7, 4);  // 8h x 32w x 128cout blocks, 196 blocks = 1 pass
  conv3x3_kernel<256, 0><<<cgrid, 256, 0, stream>>>(act16, wrc, nullptr, rc_b, rc_s,
                                                    rc_t, sig, xa);
  _Float16* xcur = xa;
  _Float16* xnxt = xb;
  for (int i = 0; i < 3; ++i) {
    conv3x3_kernel<128, 1><<<cgrid, 256, 0, stream>>>(
        xcur, wbb + (size_t)(2 * i) * 147456, nullptr, nullptr, bb_s1 + i * 128,
        bb_t1 + i * 128, nullptr, yb);
    conv3x3_kernel<128, 2><<<cgrid, 256, 0, stream>>>(
        yb, wbb + (size_t)(2 * i + 1) * 147456, xcur, nullptr, bb_s2 + i * 128,
        bb_t2 + i * 128, nullptr, xnxt);
    _Float16* t = xcur;
    xcur = xnxt;
    xnxt = t;
  }

  depth_proj_softmax_kernel<<<dim3(700), 256, 0, stream>>>(xcur, wdp, dp_b, depth16);
  gridsample_kernel<<<dim3(4096), 256, 0, stream>>>(grids, depth16, outp);
}

// Round 7
// 505.444 us; speedup vs baseline: 1.2042x; 1.2042x over previous
//
#include <hip/hip_runtime.h>
#include <math.h>

typedef _Float16 v8h __attribute__((ext_vector_type(8)));
typedef float v4f __attribute__((ext_vector_type(4)));
typedef float v16f __attribute__((ext_vector_type(16)));

// ---------------------------------------------------------------- prep (repack + mlp + convert merged)
// blocks [0,4664): weight repack  -> [c16][tap 9][khalf 2][cout 128][part 8]
// block  4664    : tiny MLP + SE sigmoid
// blocks [4665, 4665+896): NCHW f32 -> NHWC f16 convert
__global__ void __launch_bounds__(256) prep_kernel(
    const float* __restrict__ rc_w, const float* __restrict__ bb_w1,
    const float* __restrict__ bb_w2, const float* __restrict__ dp_w,
    const float* __restrict__ img, const float* __restrict__ sps,
    const float* __restrict__ fc1_w, const float* __restrict__ fc1_b,
    const float* __restrict__ fc2_w, const float* __restrict__ fc2_b,
    const float* __restrict__ se_rw, const float* __restrict__ se_rb,
    const float* __restrict__ se_ew, const float* __restrict__ se_eb,
    _Float16* __restrict__ wrc, _Float16* __restrict__ wbb,
    _Float16* __restrict__ wdp, _Float16* __restrict__ act16,
    float* __restrict__ sig) {
  const int bx = blockIdx.x;
  const int tid = threadIdx.x;
  __shared__ _Float16 tile[64][202];
  __shared__ float buf[128];

  if (bx < 4664) {  // ---- repack
    const int RC = 128 * 256 * 9;
    const int BB = 128 * 128 * 9;
    int i = bx * 256 + tid;
    if (i < RC) {
      int tap = i % 9, r = i / 9;
      int ci = r % 256, co = r / 256;
      int c = ci >> 4, kh = (ci >> 3) & 1, part = ci & 7;
      wrc[((((size_t)c * 9 + tap) * 2 + kh) * 128 + co) * 8 + part] = (_Float16)rc_w[i];
    } else if (i < RC + 6 * BB) {
      int j = i - RC;
      int blk = j / BB, k = j - blk * BB;
      int tap = k % 9, r = k / 9;
      int ci = r % 128, co = r / 128;
      const float* src = (blk < 3) ? (bb_w1 + (size_t)blk * BB) : (bb_w2 + (size_t)(blk - 3) * BB);
      int slot = (blk < 3) ? (2 * blk) : (2 * (blk - 3) + 1);
      int c = ci >> 4, kh = (ci >> 3) & 1, part = ci & 7;
      wbb[(size_t)slot * BB + ((((size_t)c * 9 + tap) * 2 + kh) * 128 + co) * 8 + part] =
          (_Float16)src[k];
    } else if (i < RC + 6 * BB + 112 * 128) {
      int j = i - RC - 6 * BB;
      wdp[j] = (_Float16)dp_w[j];
    }
  } else if (bx == 4664) {  // ---- mlp (first 128 lanes compute; barriers uniform)
    const int j = tid;
    const bool on = j < 128;
    for (int b = 0; b < 4; ++b) {
      float h1 = 0.f;
      if (on) h1 = fmaxf(sps[b] * fc1_w[j] + fc1_b[j], 0.f);
      __syncthreads();
      if (on) buf[j] = h1;
      __syncthreads();
      float hm = 0.f;
      if (on) {
        hm = fc2_b[j];
        for (int k = 0; k < 128; ++k) hm += buf[k] * fc2_w[j * 128 + k];
      }
      __syncthreads();
      if (on) buf[j] = hm;
      __syncthreads();
      float t = 0.f;
      if (on) {
        t = se_rb[j];
        for (int k = 0; k < 128; ++k) t += buf[k] * se_rw[j * 128 + k];
        t = fmaxf(t, 0.f);
      }
      __syncthreads();
      if (on) buf[j] = t;
      __syncthreads();
      if (on) {
        float se = se_eb[j];
        for (int k = 0; k < 128; ++k) se += buf[k] * se_ew[j * 128 + k];
        sig[b * 128 + j] = 1.f / (1.f + expf(-se));
      }
      __syncthreads();
    }
  } else {  // ---- convert
    const int bid = bx - 4665;
    const int cb = (bid & 3) * 64;
    const int h = (bid >> 2) % 56;
    const int n = bid / 224;
#pragma unroll 1
    for (int it = 0; it < 50; ++it) {
      int idx = it * 256 + tid;
      int c = idx / 200, w = idx - c * 200;
      tile[c][w] = (_Float16)img[(((size_t)n * 256 + cb + c) * 56 + h) * 200 + w];
    }
    __syncthreads();
#pragma unroll 1
    for (int it = 0; it < 50; ++it) {
      int idx = it * 256 + tid;
      int w = idx >> 6, c = idx & 63;
      act16[(((size_t)n * 56 + h) * 200 + w) * 256 + cb + c] = tile[c][w];
    }
  }
}

// ---------------------------------------------------------------- 3x3 conv, implicit GEMM, 32x32x16 f16 MFMA
// Tile: 8h x 32w x 64cout, grid 7x7x8 = 392 blocks (z = n*2 + cg).
//  - cout-split doubles block count vs R4 (latency-bound regime: parallelism
//    was the binding lever; R3/R6 showed block count dominates).
//  - doubled spatial tile keeps staging/output at 340/256 = 1.33x (<= R4's
//    1.4x, avoiding R3's staging duplication penalty).
// Wave = M64 (2h x 32w) x N64: per 4 MFMAs = 2 A-ds_reads + 2 B-gloads
// (halves B L2-traffic per FLOP vs R4) with acc[2][2] = 64 VGPRs (no R6 bloat).
// A: R4-proven VGPR-prefetch double-buffered LDS, R5's zero-conflict
// [part 4][pos 340]x16B layout. One barrier per 32-ch chunk.
// MODE 0: out = relu((conv + bias)*s + t) * sig_se          (rc conv)
// MODE 1: out = relu(conv*s + t)                            (bb conv1)
// MODE 2: out = relu(xprev + conv*s + t)                    (bb conv2 + residual)
template <int CIN, int MODE>
__global__ void __launch_bounds__(256, 2) conv3x3_kernel(
    const _Float16* __restrict__ act, const _Float16* __restrict__ wr,
    const _Float16* __restrict__ xprev, const float* __restrict__ bias,
    const float* __restrict__ sc, const float* __restrict__ tr,
    const float* __restrict__ sig_se, _Float16* __restrict__ out) {
  const int wt = blockIdx.x, ht = blockIdx.y;
  const int n = blockIdx.z >> 1, cg = blockIdx.z & 1;
  const int h0 = ht * 8, w0 = wt * 32;
  const int tid = threadIdx.x;
  const int wave = tid >> 6, lane = tid & 63;
  const int l31 = lane & 31, khalf = lane >> 5;

  // halo 10h x 34w, 32 ch as 4 parts of 8: [part 4][pos 340] x 16B, dbuf
  __shared__ alignas(16) _Float16 lds[2][4 * 340 * 8];

  // staging map: 1360 v8h slots over 6 rounds of 256 threads
  size_t goff[6];
  int loff[6];
  bool exist[6], ok[6];
#pragma unroll
  for (int it = 0; it < 6; ++it) {
    int slot = it * 256 + tid;
    int pos = slot >> 2, part = slot & 3;  // 4 lanes = 64B contiguous global
    int hh = pos / 34, ww = pos - hh * 34;
    int gh = h0 - 1 + hh, gw = w0 - 1 + ww;
    exist[it] = slot < 1360;
    bool inimg = (unsigned)gh < 56u && (unsigned)gw < 200u;
    ok[it] = exist[it] && inimg;
    loff[it] = (part * 340 + pos) * 8;
    int ghc = ok[it] ? gh : 0, gwc = ok[it] ? gw : 0;
    goff[it] = (((size_t)n * 56 + ghc) * 200 + gwc) * CIN + part * 8;
  }

  const v8h zero8 = {(_Float16)0, (_Float16)0, (_Float16)0, (_Float16)0,
                     (_Float16)0, (_Float16)0, (_Float16)0, (_Float16)0};
  v8h pre[6];
#pragma unroll
  for (int it = 0; it < 6; ++it) pre[it] = ok[it] ? *(const v8h*)(act + goff[it]) : zero8;

  v16f acc[2][2];
#pragma unroll
  for (int mt = 0; mt < 2; ++mt)
#pragma unroll
    for (int nt = 0; nt < 2; ++nt)
#pragma unroll
      for (int r = 0; r < 16; ++r) acc[mt][nt][r] = 0.f;

#pragma unroll 1
  for (int c0 = 0; c0 < CIN; c0 += 32) {
    _Float16* ldsb = &lds[(c0 >> 5) & 1][0];
#pragma unroll
    for (int it = 0; it < 6; ++it)
      if (exist[it]) *(v8h*)(ldsb + loff[it]) = pre[it];
    __syncthreads();
    if (c0 + 32 < CIN) {  // prefetch next chunk, hidden behind MFMA block
#pragma unroll
      for (int it = 0; it < 6; ++it)
        pre[it] = ok[it] ? *(const v8h*)(act + goff[it] + c0 + 32) : zero8;
    }
#pragma unroll
    for (int kkc = 0; kkc < 2; ++kkc) {
      const int c16 = (c0 >> 4) + kkc;
      const int apart = kkc * 2 + khalf;
#pragma unroll
      for (int dy = 0; dy < 3; ++dy) {
#pragma unroll
        for (int dx = 0; dx < 3; ++dx) {
          const int tap = dy * 3 + dx;
          const _Float16* wp =
              wr + ((((size_t)c16 * 9 + tap) * 2 + khalf) * 128 + cg * 64 + l31) * 8;
          v8h bfrag[2];
          bfrag[0] = *(const v8h*)(wp);
          bfrag[1] = *(const v8h*)(wp + 32 * 8);
#pragma unroll
          for (int mt = 0; mt < 2; ++mt) {
            const int pos = (wave * 2 + mt + dy) * 34 + l31 + dx;
            v8h afrag = *(const v8h*)(ldsb + (apart * 340 + pos) * 8);
#pragma unroll
            for (int nt = 0; nt < 2; ++nt)
              acc[mt][nt] =
                  __builtin_amdgcn_mfma_f32_32x32x16_f16(afrag, bfrag[nt], acc[mt][nt], 0, 0, 0);
          }
        }
      }
    }
  }

  // epilogue: D layout col(N=cout)=l31, row(M=w-offset)=(r&3)+8*(r>>2)+4*khalf
#pragma unroll
  for (int mt = 0; mt < 2; ++mt) {
    const int h = h0 + wave * 2 + mt;
#pragma unroll
    for (int nt = 0; nt < 2; ++nt) {
      const int cc = cg * 64 + nt * 32 + l31;
      const float s = sc[cc], t = tr[cc];
      float bb = 0.f, sg = 1.f;
      if constexpr (MODE == 0) {
        bb = bias[cc];
        sg = sig_se[n * 128 + cc];
      }
#pragma unroll
      for (int r = 0; r < 16; ++r) {
        const int m = (r & 3) + 8 * (r >> 2) + 4 * khalf;
        const int w = w0 + m;
        if (w < 200) {
          float v = acc[mt][nt][r];
          size_t oidx = (((size_t)n * 56 + h) * 200 + w) * 128 + cc;
          if constexpr (MODE == 0) v = fmaxf((v + bb) * s + t, 0.f) * sg;
          if constexpr (MODE == 1) v = fmaxf(v * s + t, 0.f);
          if constexpr (MODE == 2) v = fmaxf((float)xprev[oidx] + v * s + t, 0.f);
          out[oidx] = (_Float16)v;
        }
      }
    }
  }
}

// ---------------------------------------------------------------- depth proj (MFMA) + fused softmax
// x: [44800][128] f16; wdp: [112][128] f16; dp_b: [112] f32
// depth out: f16 [pos][112] (z-contiguous for gridsample)
__global__ void __launch_bounds__(256) depth_proj_softmax_kernel(
    const _Float16* __restrict__ x, const _Float16* __restrict__ wdp,
    const float* __restrict__ dp_b, _Float16* __restrict__ depth) {
  const int wave = threadIdx.x >> 6, lane = threadIdx.x & 63;
  const int q = lane >> 4, l16 = lane & 15;
  const int pos0 = blockIdx.x * 64 + wave * 16;

  v4f acc[7];
#pragma unroll
  for (int nt = 0; nt < 7; ++nt) {
    float bv = dp_b[nt * 16 + l16];
    acc[nt] = {bv, bv, bv, bv};
  }
#pragma unroll
  for (int c0 = 0; c0 < 128; c0 += 32) {
    v8h a = *(const v8h*)(x + (size_t)(pos0 + l16) * 128 + c0 + q * 8);
#pragma unroll
    for (int nt = 0; nt < 7; ++nt) {
      v8h b = *(const v8h*)(wdp + (size_t)(nt * 16 + l16) * 128 + c0 + q * 8);
      acc[nt] = __builtin_amdgcn_mfma_f32_16x16x32_f16(a, b, acc[nt], 0, 0, 0);
    }
  }
  float m[4];
#pragma unroll
  for (int r = 0; r < 4; ++r) {
    m[r] = acc[0][r];
#pragma unroll
    for (int nt = 1; nt < 7; ++nt) m[r] = fmaxf(m[r], acc[nt][r]);
  }
#pragma unroll
  for (int off = 1; off < 16; off <<= 1)
#pragma unroll
    for (int r = 0; r < 4; ++r) m[r] = fmaxf(m[r], __shfl_xor(m[r], off));
  float s[4] = {0.f, 0.f, 0.f, 0.f};
#pragma unroll
  for (int nt = 0; nt < 7; ++nt)
#pragma unroll
    for (int r = 0; r < 4; ++r) {
      float e = expf(acc[nt][r] - m[r]);
      acc[nt][r] = e;
      s[r] += e;
    }
#pragma unroll
  for (int off = 1; off < 16; off <<= 1)
#pragma unroll
    for (int r = 0; r < 4; ++r) s[r] += __shfl_xor(s[r], off);
#pragma unroll
  for (int r = 0; r < 4; ++r) {
    const float inv = 1.f / s[r];
    const size_t p = pos0 + q * 4 + r;
#pragma unroll
    for (int nt = 0; nt < 7; ++nt)
      depth[p * 112 + nt * 16 + l16] = (_Float16)(acc[nt][r] * inv);
  }
}

// ---------------------------------------------------------------- trilinear grid sample (C=1)
__global__ void __launch_bounds__(256) gridsample_kernel(
    const float* __restrict__ grids, const _Float16* __restrict__ depth,
    float* __restrict__ out) {
  const int i = blockIdx.x * 256 + threadIdx.x;
  const int n = i >> 18;
  const float gx = grids[(size_t)i * 3];
  const float gy = grids[(size_t)i * 3 + 1];
  const float gz = grids[(size_t)i * 3 + 2];
  const float ix = (gx + 1.f) * 100.f - 0.5f;
  const float iy = (gy + 1.f) * 28.f - 0.5f;
  const float iz = (gz + 1.f) * 56.f - 0.5f;
  const float xf = floorf(ix), yf = floorf(iy), zf = floorf(iz);
  const int x0 = (int)xf, y0 = (int)yf, z0 = (int)zf;
  const float fx = ix - xf, fy = iy - yf, fz = iz - zf;
  const bool zv0 = (unsigned)z0 < 112u;
  const bool zv1 = (unsigned)(z0 + 1) < 112u;
  const float wz0 = 1.f - fz, wz1 = fz;
  float acc = 0.f;
#pragma unroll
  for (int dy = 0; dy < 2; ++dy) {
    const int yi = y0 + dy;
    const float wy = dy ? fy : 1.f - fy;
#pragma unroll
    for (int dx = 0; dx < 2; ++dx) {
      const int xi = x0 + dx;
      const float wx = dx ? fx : 1.f - fx;
      if ((unsigned)xi < 200u && (unsigned)yi < 56u) {
        const _Float16* bp = depth + ((size_t)n * 11200 + yi * 200 + xi) * 112;
        float v0 = zv0 ? (float)bp[z0] : 0.f;
        float v1 = zv1 ? (float)bp[z0 + 1] : 0.f;
        acc += (wx * wy) * (wz0 * v0 + wz1 * v1);
      }
    }
  }
  out[i] = acc;
}

// ---------------------------------------------------------------- launch
extern "C" void kernel_launch(void* const* d_in, const int* in_sizes, int n_in,
                              void* d_out, int out_size, void* d_ws, size_t ws_size,
                              hipStream_t stream) {
  (void)in_sizes; (void)n_in; (void)out_size; (void)ws_size;
  const float* img = (const float*)d_in[0];
  const float* sps = (const float*)d_in[1];
  const float* grids = (const float*)d_in[2];
  const float* rc_w = (const float*)d_in[3];
  const float* rc_b = (const float*)d_in[4];
  const float* rc_s = (const float*)d_in[5];
  const float* rc_t = (const float*)d_in[6];
  const float* fc1_w = (const float*)d_in[7];
  const float* fc1_b = (const float*)d_in[8];
  const float* fc2_w = (const float*)d_in[9];
  const float* fc2_b = (const float*)d_in[10];
  const float* se_rw = (const float*)d_in[11];
  const float* se_rb = (const float*)d_in[12];
  const float* se_ew = (const float*)d_in[13];
  const float* se_eb = (const float*)d_in[14];
  const float* bb_w1 = (const float*)d_in[15];
  const float* bb_s1 = (const float*)d_in[16];
  const float* bb_t1 = (const float*)d_in[17];
  const float* bb_w2 = (const float*)d_in[18];
  const float* bb_s2 = (const float*)d_in[19];
  const float* bb_t2 = (const float*)d_in[20];
  const float* dp_w = (const float*)d_in[21];
  const float* dp_b = (const float*)d_in[22];
  float* outp = (float*)d_out;

  char* ws = (char*)d_ws;
  _Float16* act16 = (_Float16*)(ws + 0);
  _Float16* depth16 = (_Float16*)(ws + 0);  // reuses act16 slot (act16 dead post rc-conv)
  _Float16* xa = (_Float16*)(ws + 23068672);
  _Float16* xb = (_Float16*)(ws + 23068672 + 11534336);
  _Float16* yb = (_Float16*)(ws + 23068672 + 2 * 11534336);
  _Float16* wrc = (_Float16*)(ws + 57671680);           // 589,824 B
  _Float16* wdp = (_Float16*)(ws + 57671680 + 589824);  // 28,672 B
  _Float16* wbb = (_Float16*)(ws + 58327040);           // 1,769,472 B
  float* sig = (float*)(ws + 58327040 + 1769472);       // 2,048 B

  prep_kernel<<<dim3(5561), 256, 0, stream>>>(
      rc_w, bb_w1, bb_w2, dp_w, img, sps, fc1_w, fc1_b, fc2_w, fc2_b, se_rw, se_rb,
      se_ew, se_eb, wrc, wbb, wdp, act16, sig);

  dim3 cgrid(7, 7, 8);  // 8h x 32w x 64cout, z = n*2 + cg, 392 blocks
  conv3x3_kernel<256, 0><<<cgrid, 256, 0, stream>>>(act16, wrc, nullptr, rc_b, rc_s,
                                                    rc_t, sig, xa);
  _Float16* xcur = xa;
  _Float16* xnxt = xb;
  for (int i = 0; i < 3; ++i) {
    conv3x3_kernel<128, 1><<<cgrid, 256, 0, stream>>>(
        xcur, wbb + (size_t)(2 * i) * 147456, nullptr, nullptr, bb_s1 + i * 128,
        bb_t1 + i * 128, nullptr, yb);
    conv3x3_kernel<128, 2><<<cgrid, 256, 0, stream>>>(
        yb, wbb + (size_t)(2 * i + 1) * 147456, xcur, nullptr, bb_s2 + i * 128,
        bb_t2 + i * 128, nullptr, xnxt);
    _Float16* t = xcur;
    xcur = xnxt;
    xnxt = t;
  }

  depth_proj_softmax_kernel<<<dim3(700), 256, 0, stream>>>(xcur, wdp, dp_b, depth16);
  gridsample_kernel<<<dim3(4096), 256, 0, stream>>>(grids, depth16, outp);
}

// Round 8
// 434.415 us; speedup vs baseline: 1.4011x; 1.1635x over previous
//
#include <hip/hip_runtime.h>
#include <math.h>

typedef _Float16 v8h __attribute__((ext_vector_type(8)));
typedef float v4f __attribute__((ext_vector_type(4)));
typedef float v16f __attribute__((ext_vector_type(16)));

// ---------------------------------------------------------------- prep (repack + mlp + convert merged)
// blocks [0,4664): weight repack  -> [c16][tap 9][khalf 2][cout 128][part 8]
// block  4664    : tiny MLP + SE sigmoid
// blocks [4665, 4665+896): NCHW f32 -> NHWC f16 convert
__global__ void __launch_bounds__(256) prep_kernel(
    const float* __restrict__ rc_w, const float* __restrict__ bb_w1,
    const float* __restrict__ bb_w2, const float* __restrict__ dp_w,
    const float* __restrict__ img, const float* __restrict__ sps,
    const float* __restrict__ fc1_w, const float* __restrict__ fc1_b,
    const float* __restrict__ fc2_w, const float* __restrict__ fc2_b,
    const float* __restrict__ se_rw, const float* __restrict__ se_rb,
    const float* __restrict__ se_ew, const float* __restrict__ se_eb,
    _Float16* __restrict__ wrc, _Float16* __restrict__ wbb,
    _Float16* __restrict__ wdp, _Float16* __restrict__ act16,
    float* __restrict__ sig) {
  const int bx = blockIdx.x;
  const int tid = threadIdx.x;
  __shared__ _Float16 tile[64][202];
  __shared__ float buf[128];

  if (bx < 4664) {  // ---- repack
    const int RC = 128 * 256 * 9;
    const int BB = 128 * 128 * 9;
    int i = bx * 256 + tid;
    if (i < RC) {
      int tap = i % 9, r = i / 9;
      int ci = r % 256, co = r / 256;
      int c = ci >> 4, kh = (ci >> 3) & 1, part = ci & 7;
      wrc[((((size_t)c * 9 + tap) * 2 + kh) * 128 + co) * 8 + part] = (_Float16)rc_w[i];
    } else if (i < RC + 6 * BB) {
      int j = i - RC;
      int blk = j / BB, k = j - blk * BB;
      int tap = k % 9, r = k / 9;
      int ci = r % 128, co = r / 128;
      const float* src = (blk < 3) ? (bb_w1 + (size_t)blk * BB) : (bb_w2 + (size_t)(blk - 3) * BB);
      int slot = (blk < 3) ? (2 * blk) : (2 * (blk - 3) + 1);
      int c = ci >> 4, kh = (ci >> 3) & 1, part = ci & 7;
      wbb[(size_t)slot * BB + ((((size_t)c * 9 + tap) * 2 + kh) * 128 + co) * 8 + part] =
          (_Float16)src[k];
    } else if (i < RC + 6 * BB + 112 * 128) {
      int j = i - RC - 6 * BB;
      wdp[j] = (_Float16)dp_w[j];
    }
  } else if (bx == 4664) {  // ---- mlp (first 128 lanes compute; barriers uniform)
    const int j = tid;
    const bool on = j < 128;
    for (int b = 0; b < 4; ++b) {
      float h1 = 0.f;
      if (on) h1 = fmaxf(sps[b] * fc1_w[j] + fc1_b[j], 0.f);
      __syncthreads();
      if (on) buf[j] = h1;
      __syncthreads();
      float hm = 0.f;
      if (on) {
        hm = fc2_b[j];
        for (int k = 0; k < 128; ++k) hm += buf[k] * fc2_w[j * 128 + k];
      }
      __syncthreads();
      if (on) buf[j] = hm;
      __syncthreads();
      float t = 0.f;
      if (on) {
        t = se_rb[j];
        for (int k = 0; k < 128; ++k) t += buf[k] * se_rw[j * 128 + k];
        t = fmaxf(t, 0.f);
      }
      __syncthreads();
      if (on) buf[j] = t;
      __syncthreads();
      if (on) {
        float se = se_eb[j];
        for (int k = 0; k < 128; ++k) se += buf[k] * se_ew[j * 128 + k];
        sig[b * 128 + j] = 1.f / (1.f + expf(-se));
      }
      __syncthreads();
    }
  } else {  // ---- convert
    const int bid = bx - 4665;
    const int cb = (bid & 3) * 64;
    const int h = (bid >> 2) % 56;
    const int n = bid / 224;
#pragma unroll 1
    for (int it = 0; it < 50; ++it) {
      int idx = it * 256 + tid;
      int c = idx / 200, w = idx - c * 200;
      tile[c][w] = (_Float16)img[(((size_t)n * 256 + cb + c) * 56 + h) * 200 + w];
    }
    __syncthreads();
#pragma unroll 1
    for (int it = 0; it < 50; ++it) {
      int idx = it * 256 + tid;
      int w = idx >> 6, c = idx & 63;
      act16[(((size_t)n * 56 + h) * 200 + w) * 256 + cb + c] = tile[c][w];
    }
  }
}

// ---------------------------------------------------------------- 3x3 conv, implicit GEMM, 32x32x16 f16 MFMA
// Tile: 8h x 32w x 64cout, grid 7x7x8 = 392 blocks (z = n*2 + cg), 2 blocks/CU.
// KEY CHANGE vs R7: B-fragments come from LDS, not per-wave L2 refetch.
// R7 counters showed the inner loop serialized on ~200cy B-gload latency per
// tap (VGPR=84 blocked compiler hoisting); B LDS traffic is amortized per
// block (294 KB) vs per wave (1.15 MB), and all inner-loop memory ops become
// pipelineable ds_read_b128.
// Chunk = 16 channels. Per chunk the block VGPR-prefetches (during previous
// chunk's compute) and commits to double-buffered LDS:
//   A halo [part 2][pos 340]x16B  (10.9 KB/buf, 3 x 16B/thread)
//   B slice [tap 9][kh 2][cout 64]x16B (18.4 KB/buf, 5 x 16B/thread)
// One barrier per chunk. LDS total 58.6 KB -> 2 blocks/CU co-resident.
// Wave = M64 (2h x 32w) x N64; per tap: 2 B + 2 A ds_reads, 4 MFMAs.
// MODE 0: out = relu((conv + bias)*s + t) * sig_se          (rc conv)
// MODE 1: out = relu(conv*s + t)                            (bb conv1)
// MODE 2: out = relu(xprev + conv*s + t)                    (bb conv2 + residual)
template <int CIN, int MODE>
__global__ void __launch_bounds__(256, 2) conv3x3_kernel(
    const _Float16* __restrict__ act, const _Float16* __restrict__ wr,
    const _Float16* __restrict__ xprev, const float* __restrict__ bias,
    const float* __restrict__ sc, const float* __restrict__ tr,
    const float* __restrict__ sig_se, _Float16* __restrict__ out) {
  constexpr int NCH = CIN / 16;
  const int wt = blockIdx.x, ht = blockIdx.y;
  const int n = blockIdx.z >> 1, cg = blockIdx.z & 1;
  const int h0 = ht * 8, w0 = wt * 32;
  const int tid = threadIdx.x;
  const int wave = tid >> 6, lane = tid & 63;
  const int l31 = lane & 31, khalf = lane >> 5;

  __shared__ alignas(16) _Float16 ldsA[2][2 * 340 * 8];  // 10,880 B per buf
  __shared__ alignas(16) _Float16 ldsB[2][1152 * 8];     // 18,432 B per buf

  // ---- A staging map: 680 v8h slots (2 parts x 340 pos) over 3 rounds
  size_t goffA[3];
  int loffA[3];
  bool exA[3], okA[3];
#pragma unroll
  for (int it = 0; it < 3; ++it) {
    int slot = it * 256 + tid;
    int pos = slot >> 1, part = slot & 1;  // 2 lanes = 32B contiguous global
    int hh = pos / 34, ww = pos - hh * 34;
    int gh = h0 - 1 + hh, gw = w0 - 1 + ww;
    exA[it] = slot < 680;
    bool inimg = (unsigned)gh < 56u && (unsigned)gw < 200u;
    okA[it] = exA[it] && inimg;
    loffA[it] = (part * 340 + pos) * 8;
    int ghc = okA[it] ? gh : 0, gwc = okA[it] ? gw : 0;
    goffA[it] = (((size_t)n * 56 + ghc) * 200 + gwc) * CIN + part * 8;
  }
  // ---- B staging map: 1152 v8h slots (9 tap x 2 kh x 64 cout) over 5 rounds
  size_t goffB[5];
  int loffB[5];
  bool exB[5];
#pragma unroll
  for (int it = 0; it < 5; ++it) {
    int slot = it * 256 + tid;
    exB[it] = slot < 1152;
    int s = exB[it] ? slot : 0;
    int tap = s >> 7, kh = (s >> 6) & 1, co = s & 63;
    goffB[it] = (((size_t)(tap * 2 + kh)) * 128 + cg * 64 + co) * 8;  // chunk-0 offset
    loffB[it] = s * 8;
  }

  const v8h zero8 = {(_Float16)0, (_Float16)0, (_Float16)0, (_Float16)0,
                     (_Float16)0, (_Float16)0, (_Float16)0, (_Float16)0};
  v8h preA[3], preB[5];
#pragma unroll
  for (int it = 0; it < 3; ++it) preA[it] = okA[it] ? *(const v8h*)(act + goffA[it]) : zero8;
#pragma unroll
  for (int it = 0; it < 5; ++it) preB[it] = *(const v8h*)(wr + goffB[it]);

  v16f acc[2][2];
#pragma unroll
  for (int mt = 0; mt < 2; ++mt)
#pragma unroll
    for (int nt = 0; nt < 2; ++nt)
#pragma unroll
      for (int r = 0; r < 16; ++r) acc[mt][nt][r] = 0.f;

#pragma unroll 1
  for (int c = 0; c < NCH; ++c) {
    _Float16* aB = &ldsA[c & 1][0];
    _Float16* bB = &ldsB[c & 1][0];
    // commit prefetched chunk
#pragma unroll
    for (int it = 0; it < 3; ++it)
      if (exA[it]) *(v8h*)(aB + loffA[it]) = preA[it];
#pragma unroll
    for (int it = 0; it < 5; ++it)
      if (exB[it]) *(v8h*)(bB + loffB[it]) = preB[it];
    __syncthreads();
    // prefetch next chunk (batched; hidden behind this chunk's MFMA block)
    if (c + 1 < NCH) {
#pragma unroll
      for (int it = 0; it < 3; ++it)
        preA[it] = okA[it] ? *(const v8h*)(act + goffA[it] + (size_t)(c + 1) * 16) : zero8;
#pragma unroll
      for (int it = 0; it < 5; ++it)
        preB[it] = *(const v8h*)(wr + goffB[it] + (size_t)(c + 1) * 18432);
    }
#pragma unroll
    for (int dy = 0; dy < 3; ++dy) {
#pragma unroll
      for (int dx = 0; dx < 3; ++dx) {
        const int tap = dy * 3 + dx;
        v8h bfrag[2];
        bfrag[0] = *(const v8h*)(bB + (tap * 128 + khalf * 64 + l31) * 8);
        bfrag[1] = *(const v8h*)(bB + (tap * 128 + khalf * 64 + 32 + l31) * 8);
#pragma unroll
        for (int mt = 0; mt < 2; ++mt) {
          const int pos = (wave * 2 + mt + dy) * 34 + l31 + dx;
          v8h afrag = *(const v8h*)(aB + (khalf * 340 + pos) * 8);
#pragma unroll
          for (int nt = 0; nt < 2; ++nt)
            acc[mt][nt] =
                __builtin_amdgcn_mfma_f32_32x32x16_f16(afrag, bfrag[nt], acc[mt][nt], 0, 0, 0);
        }
      }
    }
  }

  // epilogue: D layout col(N=cout)=l31, row(M=w-offset)=(r&3)+8*(r>>2)+4*khalf
#pragma unroll
  for (int mt = 0; mt < 2; ++mt) {
    const int h = h0 + wave * 2 + mt;
#pragma unroll
    for (int nt = 0; nt < 2; ++nt) {
      const int cc = cg * 64 + nt * 32 + l31;
      const float s = sc[cc], t = tr[cc];
      float bb = 0.f, sg = 1.f;
      if constexpr (MODE == 0) {
        bb = bias[cc];
        sg = sig_se[n * 128 + cc];
      }
#pragma unroll
      for (int r = 0; r < 16; ++r) {
        const int m = (r & 3) + 8 * (r >> 2) + 4 * khalf;
        const int w = w0 + m;
        if (w < 200) {
          float v = acc[mt][nt][r];
          size_t oidx = (((size_t)n * 56 + h) * 200 + w) * 128 + cc;
          if constexpr (MODE == 0) v = fmaxf((v + bb) * s + t, 0.f) * sg;
          if constexpr (MODE == 1) v = fmaxf(v * s + t, 0.f);
          if constexpr (MODE == 2) v = fmaxf((float)xprev[oidx] + v * s + t, 0.f);
          out[oidx] = (_Float16)v;
        }
      }
    }
  }
}

// ---------------------------------------------------------------- depth proj (MFMA) + fused softmax
// x: [44800][128] f16; wdp: [112][128] f16; dp_b: [112] f32
// depth out: f16 [pos][112] (z-contiguous for gridsample)
__global__ void __launch_bounds__(256) depth_proj_softmax_kernel(
    const _Float16* __restrict__ x, const _Float16* __restrict__ wdp,
    const float* __restrict__ dp_b, _Float16* __restrict__ depth) {
  const int wave = threadIdx.x >> 6, lane = threadIdx.x & 63;
  const int q = lane >> 4, l16 = lane & 15;
  const int pos0 = blockIdx.x * 64 + wave * 16;

  v4f acc[7];
#pragma unroll
  for (int nt = 0; nt < 7; ++nt) {
    float bv = dp_b[nt * 16 + l16];
    acc[nt] = {bv, bv, bv, bv};
  }
#pragma unroll
  for (int c0 = 0; c0 < 128; c0 += 32) {
    v8h a = *(const v8h*)(x + (size_t)(pos0 + l16) * 128 + c0 + q * 8);
#pragma unroll
    for (int nt = 0; nt < 7; ++nt) {
      v8h b = *(const v8h*)(wdp + (size_t)(nt * 16 + l16) * 128 + c0 + q * 8);
      acc[nt] = __builtin_amdgcn_mfma_f32_16x16x32_f16(a, b, acc[nt], 0, 0, 0);
    }
  }
  float m[4];
#pragma unroll
  for (int r = 0; r < 4; ++r) {
    m[r] = acc[0][r];
#pragma unroll
    for (int nt = 1; nt < 7; ++nt) m[r] = fmaxf(m[r], acc[nt][r]);
  }
#pragma unroll
  for (int off = 1; off < 16; off <<= 1)
#pragma unroll
    for (int r = 0; r < 4; ++r) m[r] = fmaxf(m[r], __shfl_xor(m[r], off));
  float s[4] = {0.f, 0.f, 0.f, 0.f};
#pragma unroll
  for (int nt = 0; nt < 7; ++nt)
#pragma unroll
    for (int r = 0; r < 4; ++r) {
      float e = expf(acc[nt][r] - m[r]);
      acc[nt][r] = e;
      s[r] += e;
    }
#pragma unroll
  for (int off = 1; off < 16; off <<= 1)
#pragma unroll
    for (int r = 0; r < 4; ++r) s[r] += __shfl_xor(s[r], off);
#pragma unroll
  for (int r = 0; r < 4; ++r) {
    const float inv = 1.f / s[r];
    const size_t p = pos0 + q * 4 + r;
#pragma unroll
    for (int nt = 0; nt < 7; ++nt)
      depth[p * 112 + nt * 16 + l16] = (_Float16)(acc[nt][r] * inv);
  }
}

// ---------------------------------------------------------------- trilinear grid sample (C=1)
__global__ void __launch_bounds__(256) gridsample_kernel(
    const float* __restrict__ grids, const _Float16* __restrict__ depth,
    float* __restrict__ out) {
  const int i = blockIdx.x * 256 + threadIdx.x;
  const int n = i >> 18;
  const float gx = grids[(size_t)i * 3];
  const float gy = grids[(size_t)i * 3 + 1];
  const float gz = grids[(size_t)i * 3 + 2];
  const float ix = (gx + 1.f) * 100.f - 0.5f;
  const float iy = (gy + 1.f) * 28.f - 0.5f;
  const float iz = (gz + 1.f) * 56.f - 0.5f;
  const float xf = floorf(ix), yf = floorf(iy), zf = floorf(iz);
  const int x0 = (int)xf, y0 = (int)yf, z0 = (int)zf;
  const float fx = ix - xf, fy = iy - yf, fz = iz - zf;
  const bool zv0 = (unsigned)z0 < 112u;
  const bool zv1 = (unsigned)(z0 + 1) < 112u;
  const float wz0 = 1.f - fz, wz1 = fz;
  float acc = 0.f;
#pragma unroll
  for (int dy = 0; dy < 2; ++dy) {
    const int yi = y0 + dy;
    const float wy = dy ? fy : 1.f - fy;
#pragma unroll
    for (int dx = 0; dx < 2; ++dx) {
      const int xi = x0 + dx;
      const float wx = dx ? fx : 1.f - fx;
      if ((unsigned)xi < 200u && (unsigned)yi < 56u) {
        const _Float16* bp = depth + ((size_t)n * 11200 + yi * 200 + xi) * 112;
        float v0 = zv0 ? (float)bp[z0] : 0.f;
        float v1 = zv1 ? (float)bp[z0 + 1] : 0.f;
        acc += (wx * wy) * (wz0 * v0 + wz1 * v1);
      }
    }
  }
  out[i] = acc;
}

// ---------------------------------------------------------------- launch
extern "C" void kernel_launch(void* const* d_in, const int* in_sizes, int n_in,
                              void* d_out, int out_size, void* d_ws, size_t ws_size,
                              hipStream_t stream) {
  (void)in_sizes; (void)n_in; (void)out_size; (void)ws_size;
  const float* img = (const float*)d_in[0];
  const float* sps = (const float*)d_in[1];
  const float* grids = (const float*)d_in[2];
  const float* rc_w = (const float*)d_in[3];
  const float* rc_b = (const float*)d_in[4];
  const float* rc_s = (const float*)d_in[5];
  const float* rc_t = (const float*)d_in[6];
  const float* fc1_w = (const float*)d_in[7];
  const float* fc1_b = (const float*)d_in[8];
  const float* fc2_w = (const float*)d_in[9];
  const float* fc2_b = (const float*)d_in[10];
  const float* se_rw = (const float*)d_in[11];
  const float* se_rb = (const float*)d_in[12];
  const float* se_ew = (const float*)d_in[13];
  const float* se_eb = (const float*)d_in[14];
  const float* bb_w1 = (const float*)d_in[15];
  const float* bb_s1 = (const float*)d_in[16];
  const float* bb_t1 = (const float*)d_in[17];
  const float* bb_w2 = (const float*)d_in[18];
  const float* bb_s2 = (const float*)d_in[19];
  const float* bb_t2 = (const float*)d_in[20];
  const float* dp_w = (const float*)d_in[21];
  const float* dp_b = (const float*)d_in[22];
  float* outp = (float*)d_out;

  char* ws = (char*)d_ws;
  _Float16* act16 = (_Float16*)(ws + 0);
  _Float16* depth16 = (_Float16*)(ws + 0);  // reuses act16 slot (act16 dead post rc-conv)
  _Float16* xa = (_Float16*)(ws + 23068672);
  _Float16* xb = (_Float16*)(ws + 23068672 + 11534336);
  _Float16* yb = (_Float16*)(ws + 23068672 + 2 * 11534336);
  _Float16* wrc = (_Float16*)(ws + 57671680);           // 589,824 B
  _Float16* wdp = (_Float16*)(ws + 57671680 + 589824);  // 28,672 B
  _Float16* wbb = (_Float16*)(ws + 58327040);           // 1,769,472 B
  float* sig = (float*)(ws + 58327040 + 1769472);       // 2,048 B

  prep_kernel<<<dim3(5561), 256, 0, stream>>>(
      rc_w, bb_w1, bb_w2, dp_w, img, sps, fc1_w, fc1_b, fc2_w, fc2_b, se_rw, se_rb,
      se_ew, se_eb, wrc, wbb, wdp, act16, sig);

  dim3 cgrid(7, 7, 8);  // 8h x 32w x 64cout, z = n*2 + cg, 392 blocks
  conv3x3_kernel<256, 0><<<cgrid, 256, 0, stream>>>(act16, wrc, nullptr, rc_b, rc_s,
                                                    rc_t, sig, xa);
  _Float16* xcur = xa;
  _Float16* xnxt = xb;
  for (int i = 0; i < 3; ++i) {
    conv3x3_kernel<128, 1><<<cgrid, 256, 0, stream>>>(
        xcur, wbb + (size_t)(2 * i) * 147456, nullptr, nullptr, bb_s1 + i * 128,
        bb_t1 + i * 128, nullptr, yb);
    conv3x3_kernel<128, 2><<<cgrid, 256, 0, stream>>>(
        yb, wbb + (size_t)(2 * i + 1) * 147456, xcur, nullptr, bb_s2 + i * 128,
        bb_t2 + i * 128, nullptr, xnxt);
    _Float16* t = xcur;
    xcur = xnxt;
    xnxt = t;
  }

  depth_proj_softmax_kernel<<<dim3(700), 256, 0, stream>>>(xcur, wdp, dp_b, depth16);
  gridsample_kernel<<<dim3(4096), 256, 0, stream>>>(grids, depth16, outp);
}

// Round 9
// 425.693 us; speedup vs baseline: 1.4299x; 1.0205x over previous
//
#include <hip/hip_runtime.h>
#include <math.h>

typedef _Float16 v8h __attribute__((ext_vector_type(8)));
typedef float v4f __attribute__((ext_vector_type(4)));
typedef float v16f __attribute__((ext_vector_type(16)));

// ---------------------------------------------------------------- prep (repack + mlp + convert merged)
// blocks [0,583): vectorized weight repack (slot order == dest layout order;
//                 16B coalesced stores, 8 strided f32 gathers per thread)
// block  583    : tiny MLP + SE sigmoid
// blocks [584,584+224): NCHW f32 -> NHWC f16 convert, thread=w, v8h stores
__global__ void __launch_bounds__(256) prep_kernel(
    const float* __restrict__ rc_w, const float* __restrict__ bb_w1,
    const float* __restrict__ bb_w2, const float* __restrict__ dp_w,
    const float* __restrict__ img, const float* __restrict__ sps,
    const float* __restrict__ fc1_w, const float* __restrict__ fc1_b,
    const float* __restrict__ fc2_w, const float* __restrict__ fc2_b,
    const float* __restrict__ se_rw, const float* __restrict__ se_rb,
    const float* __restrict__ se_ew, const float* __restrict__ se_eb,
    _Float16* __restrict__ wrc, _Float16* __restrict__ wbb,
    _Float16* __restrict__ wdp, _Float16* __restrict__ act16,
    float* __restrict__ sig) {
  const int bx = blockIdx.x;
  const int tid = threadIdx.x;
  __shared__ float buf[128];

  if (bx < 583) {  // ---- repack, one v8h per thread
    int slot = bx * 256 + tid;  // 149,248 total v8h slots
    if (slot < 36864) {
      // rc: dest layout [c16 16][tap 9][kh 2][co 128][part 8]; slot == dest order
      int co = slot & 127;
      int r = slot >> 7;
      int kh = r & 1;
      r >>= 1;
      int tap = r % 9, c16 = r / 9;
      int cibase = c16 * 16 + kh * 8;
      v8h o;
#pragma unroll
      for (int j = 0; j < 8; ++j)
        o[j] = (_Float16)rc_w[((size_t)co * 256 + cibase + j) * 9 + tap];
      *(v8h*)(wrc + (size_t)slot * 8) = o;
    } else if (slot < 147456) {
      int s2 = slot - 36864;  // 6 convs x 18,432 slots
      int blk = s2 / 18432, r2 = s2 - blk * 18432;
      int co = r2 & 127;
      int r = r2 >> 7;
      int kh = r & 1;
      r >>= 1;
      int tap = r % 9, c16 = r / 9;
      int cibase = c16 * 16 + kh * 8;
      const float* src = (blk < 3) ? (bb_w1 + (size_t)blk * 147456)
                                   : (bb_w2 + (size_t)(blk - 3) * 147456);
      int cslot = (blk < 3) ? (2 * blk) : (2 * (blk - 3) + 1);
      v8h o;
#pragma unroll
      for (int j = 0; j < 8; ++j)
        o[j] = (_Float16)src[((size_t)co * 128 + cibase + j) * 9 + tap];
      *(v8h*)(wbb + ((size_t)cslot * 18432 + r2) * 8) = o;
    } else if (slot < 149248) {
      int s3 = slot - 147456;  // dp: flat, coalesced both sides
      v8h o;
#pragma unroll
      for (int j = 0; j < 8; ++j) o[j] = (_Float16)dp_w[(size_t)s3 * 8 + j];
      *(v8h*)(wdp + (size_t)s3 * 8) = o;
    }
  } else if (bx == 583) {  // ---- mlp (first 128 lanes compute; barriers uniform)
    const int j = tid;
    const bool on = j < 128;
    for (int b = 0; b < 4; ++b) {
      float h1 = 0.f;
      if (on) h1 = fmaxf(sps[b] * fc1_w[j] + fc1_b[j], 0.f);
      __syncthreads();
      if (on) buf[j] = h1;
      __syncthreads();
      float hm = 0.f;
      if (on) {
        hm = fc2_b[j];
        for (int k = 0; k < 128; ++k) hm += buf[k] * fc2_w[j * 128 + k];
      }
      __syncthreads();
      if (on) buf[j] = hm;
      __syncthreads();
      float t = 0.f;
      if (on) {
        t = se_rb[j];
        for (int k = 0; k < 128; ++k) t += buf[k] * se_rw[j * 128 + k];
        t = fmaxf(t, 0.f);
      }
      __syncthreads();
      if (on) buf[j] = t;
      __syncthreads();
      if (on) {
        float se = se_eb[j];
        for (int k = 0; k < 128; ++k) se += buf[k] * se_ew[j * 128 + k];
        sig[b * 128 + j] = 1.f / (1.f + expf(-se));
      }
      __syncthreads();
    }
  } else {  // ---- convert: block = (n,h); thread = w; 8-ch gather -> v8h store
    const int bid = bx - 584;
    const int n = bid / 56, h = bid - n * 56;
    const int w = tid;
    if (w < 200) {
      const float* ip = img + ((size_t)n * 256 * 56 + h) * 200 + w;
      _Float16* op = act16 + (((size_t)n * 56 + h) * 200 + w) * 256;
#pragma unroll 4
      for (int c8 = 0; c8 < 32; ++c8) {
        v8h o;
#pragma unroll
        for (int j = 0; j < 8; ++j)
          o[j] = (_Float16)ip[(size_t)(c8 * 8 + j) * 11200];  // 56*200
        *(v8h*)(op + c8 * 8) = o;
      }
    }
  }
}

// ---------------------------------------------------------------- 3x3 conv, implicit GEMM, 32x32x16 f16 MFMA
// Tile: 8h x 32w x 64cout, grid 7x7x8 = 392 blocks (z = n*2 + cg), 2 blocks/CU.
// B-fragments from double-buffered LDS (R8 win: B LDS traffic amortized per
// block, inner loop all pipelineable ds_read_b128). Chunk = 16 channels;
// block VGPR-prefetches A halo (3x16B/thread) + B slice (5x16B/thread) during
// previous chunk's compute; one barrier per chunk. LDS 58.6 KB -> 2 blocks/CU.
// Wave = M64 (2h x 32w) x N64; per tap: 2 B + 2 A ds_reads, 4 MFMAs.
// MODE 0: out = relu((conv + bias)*s + t) * sig_se          (rc conv)
// MODE 1: out = relu(conv*s + t)                            (bb conv1)
// MODE 2: out = relu(xprev + conv*s + t)                    (bb conv2 + residual)
template <int CIN, int MODE>
__global__ void __launch_bounds__(256, 2) conv3x3_kernel(
    const _Float16* __restrict__ act, const _Float16* __restrict__ wr,
    const _Float16* __restrict__ xprev, const float* __restrict__ bias,
    const float* __restrict__ sc, const float* __restrict__ tr,
    const float* __restrict__ sig_se, _Float16* __restrict__ out) {
  constexpr int NCH = CIN / 16;
  const int wt = blockIdx.x, ht = blockIdx.y;
  const int n = blockIdx.z >> 1, cg = blockIdx.z & 1;
  const int h0 = ht * 8, w0 = wt * 32;
  const int tid = threadIdx.x;
  const int wave = tid >> 6, lane = tid & 63;
  const int l31 = lane & 31, khalf = lane >> 5;

  __shared__ alignas(16) _Float16 ldsA[2][2 * 340 * 8];  // 10,880 B per buf
  __shared__ alignas(16) _Float16 ldsB[2][1152 * 8];     // 18,432 B per buf

  // ---- A staging map: 680 v8h slots (2 parts x 340 pos) over 3 rounds
  size_t goffA[3];
  int loffA[3];
  bool exA[3], okA[3];
#pragma unroll
  for (int it = 0; it < 3; ++it) {
    int slot = it * 256 + tid;
    int pos = slot >> 1, part = slot & 1;  // 2 lanes = 32B contiguous global
    int hh = pos / 34, ww = pos - hh * 34;
    int gh = h0 - 1 + hh, gw = w0 - 1 + ww;
    exA[it] = slot < 680;
    bool inimg = (unsigned)gh < 56u && (unsigned)gw < 200u;
    okA[it] = exA[it] && inimg;
    loffA[it] = (part * 340 + pos) * 8;
    int ghc = okA[it] ? gh : 0, gwc = okA[it] ? gw : 0;
    goffA[it] = (((size_t)n * 56 + ghc) * 200 + gwc) * CIN + part * 8;
  }
  // ---- B staging map: 1152 v8h slots (9 tap x 2 kh x 64 cout) over 5 rounds
  size_t goffB[5];
  int loffB[5];
  bool exB[5];
#pragma unroll
  for (int it = 0; it < 5; ++it) {
    int slot = it * 256 + tid;
    exB[it] = slot < 1152;
    int s = exB[it] ? slot : 0;
    int tap = s >> 7, kh = (s >> 6) & 1, co = s & 63;
    goffB[it] = (((size_t)(tap * 2 + kh)) * 128 + cg * 64 + co) * 8;  // chunk-0 offset
    loffB[it] = s * 8;
  }

  const v8h zero8 = {(_Float16)0, (_Float16)0, (_Float16)0, (_Float16)0,
                     (_Float16)0, (_Float16)0, (_Float16)0, (_Float16)0};
  v8h preA[3], preB[5];
#pragma unroll
  for (int it = 0; it < 3; ++it) preA[it] = okA[it] ? *(const v8h*)(act + goffA[it]) : zero8;
#pragma unroll
  for (int it = 0; it < 5; ++it) preB[it] = *(const v8h*)(wr + goffB[it]);

  v16f acc[2][2];
#pragma unroll
  for (int mt = 0; mt < 2; ++mt)
#pragma unroll
    for (int nt = 0; nt < 2; ++nt)
#pragma unroll
      for (int r = 0; r < 16; ++r) acc[mt][nt][r] = 0.f;

#pragma unroll 1
  for (int c = 0; c < NCH; ++c) {
    _Float16* aB = &ldsA[c & 1][0];
    _Float16* bB = &ldsB[c & 1][0];
    // commit prefetched chunk
#pragma unroll
    for (int it = 0; it < 3; ++it)
      if (exA[it]) *(v8h*)(aB + loffA[it]) = preA[it];
#pragma unroll
    for (int it = 0; it < 5; ++it)
      if (exB[it]) *(v8h*)(bB + loffB[it]) = preB[it];
    __syncthreads();
    // prefetch next chunk (batched; hidden behind this chunk's MFMA block)
    if (c + 1 < NCH) {
#pragma unroll
      for (int it = 0; it < 3; ++it)
        preA[it] = okA[it] ? *(const v8h*)(act + goffA[it] + (size_t)(c + 1) * 16) : zero8;
#pragma unroll
      for (int it = 0; it < 5; ++it)
        preB[it] = *(const v8h*)(wr + goffB[it] + (size_t)(c + 1) * 18432);
    }
#pragma unroll
    for (int dy = 0; dy < 3; ++dy) {
#pragma unroll
      for (int dx = 0; dx < 3; ++dx) {
        const int tap = dy * 3 + dx;
        v8h bfrag[2];
        bfrag[0] = *(const v8h*)(bB + (tap * 128 + khalf * 64 + l31) * 8);
        bfrag[1] = *(const v8h*)(bB + (tap * 128 + khalf * 64 + 32 + l31) * 8);
#pragma unroll
        for (int mt = 0; mt < 2; ++mt) {
          const int pos = (wave * 2 + mt + dy) * 34 + l31 + dx;
          v8h afrag = *(const v8h*)(aB + (khalf * 340 + pos) * 8);
#pragma unroll
          for (int nt = 0; nt < 2; ++nt)
            acc[mt][nt] =
                __builtin_amdgcn_mfma_f32_32x32x16_f16(afrag, bfrag[nt], acc[mt][nt], 0, 0, 0);
        }
      }
    }
  }

  // epilogue: D layout col(N=cout)=l31, row(M=w-offset)=(r&3)+8*(r>>2)+4*khalf
#pragma unroll
  for (int mt = 0; mt < 2; ++mt) {
    const int h = h0 + wave * 2 + mt;
#pragma unroll
    for (int nt = 0; nt < 2; ++nt) {
      const int cc = cg * 64 + nt * 32 + l31;
      const float s = sc[cc], t = tr[cc];
      float bb = 0.f, sg = 1.f;
      if constexpr (MODE == 0) {
        bb = bias[cc];
        sg = sig_se[n * 128 + cc];
      }
#pragma unroll
      for (int r = 0; r < 16; ++r) {
        const int m = (r & 3) + 8 * (r >> 2) + 4 * khalf;
        const int w = w0 + m;
        if (w < 200) {
          float v = acc[mt][nt][r];
          size_t oidx = (((size_t)n * 56 + h) * 200 + w) * 128 + cc;
          if constexpr (MODE == 0) v = fmaxf((v + bb) * s + t, 0.f) * sg;
          if constexpr (MODE == 1) v = fmaxf(v * s + t, 0.f);
          if constexpr (MODE == 2) v = fmaxf((float)xprev[oidx] + v * s + t, 0.f);
          out[oidx] = (_Float16)v;
        }
      }
    }
  }
}

// ---------------------------------------------------------------- depth proj (MFMA) + fused softmax
// x: [44800][128] f16; wdp: [112][128] f16; dp_b: [112] f32
// depth out: f16 [pos][112] (z-contiguous for gridsample)
__global__ void __launch_bounds__(256) depth_proj_softmax_kernel(
    const _Float16* __restrict__ x, const _Float16* __restrict__ wdp,
    const float* __restrict__ dp_b, _Float16* __restrict__ depth) {
  const int wave = threadIdx.x >> 6, lane = threadIdx.x & 63;
  const int q = lane >> 4, l16 = lane & 15;
  const int pos0 = blockIdx.x * 64 + wave * 16;

  v4f acc[7];
#pragma unroll
  for (int nt = 0; nt < 7; ++nt) {
    float bv = dp_b[nt * 16 + l16];
    acc[nt] = {bv, bv, bv, bv};
  }
#pragma unroll
  for (int c0 = 0; c0 < 128; c0 += 32) {
    v8h a = *(const v8h*)(x + (size_t)(pos0 + l16) * 128 + c0 + q * 8);
#pragma unroll
    for (int nt = 0; nt < 7; ++nt) {
      v8h b = *(const v8h*)(wdp + (size_t)(nt * 16 + l16) * 128 + c0 + q * 8);
      acc[nt] = __builtin_amdgcn_mfma_f32_16x16x32_f16(a, b, acc[nt], 0, 0, 0);
    }
  }
  float m[4];
#pragma unroll
  for (int r = 0; r < 4; ++r) {
    m[r] = acc[0][r];
#pragma unroll
    for (int nt = 1; nt < 7; ++nt) m[r] = fmaxf(m[r], acc[nt][r]);
  }
#pragma unroll
  for (int off = 1; off < 16; off <<= 1)
#pragma unroll
    for (int r = 0; r < 4; ++r) m[r] = fmaxf(m[r], __shfl_xor(m[r], off));
  float s[4] = {0.f, 0.f, 0.f, 0.f};
#pragma unroll
  for (int nt = 0; nt < 7; ++nt)
#pragma unroll
    for (int r = 0; r < 4; ++r) {
      float e = expf(acc[nt][r] - m[r]);
      acc[nt][r] = e;
      s[r] += e;
    }
#pragma unroll
  for (int off = 1; off < 16; off <<= 1)
#pragma unroll
    for (int r = 0; r < 4; ++r) s[r] += __shfl_xor(s[r], off);
#pragma unroll
  for (int r = 0; r < 4; ++r) {
    const float inv = 1.f / s[r];
    const size_t p = pos0 + q * 4 + r;
#pragma unroll
    for (int nt = 0; nt < 7; ++nt)
      depth[p * 112 + nt * 16 + l16] = (_Float16)(acc[nt][r] * inv);
  }
}

// ---------------------------------------------------------------- trilinear grid sample (C=1)
__global__ void __launch_bounds__(256) gridsample_kernel(
    const float* __restrict__ grids, const _Float16* __restrict__ depth,
    float* __restrict__ out) {
  const int i = blockIdx.x * 256 + threadIdx.x;
  const int n = i >> 18;
  const float gx = grids[(size_t)i * 3];
  const float gy = grids[(size_t)i * 3 + 1];
  const float gz = grids[(size_t)i * 3 + 2];
  const float ix = (gx + 1.f) * 100.f - 0.5f;
  const float iy = (gy + 1.f) * 28.f - 0.5f;
  const float iz = (gz + 1.f) * 56.f - 0.5f;
  const float xf = floorf(ix), yf = floorf(iy), zf = floorf(iz);
  const int x0 = (int)xf, y0 = (int)yf, z0 = (int)zf;
  const float fx = ix - xf, fy = iy - yf, fz = iz - zf;
  const bool zv0 = (unsigned)z0 < 112u;
  const bool zv1 = (unsigned)(z0 + 1) < 112u;
  const float wz0 = 1.f - fz, wz1 = fz;
  float acc = 0.f;
#pragma unroll
  for (int dy = 0; dy < 2; ++dy) {
    const int yi = y0 + dy;
    const float wy = dy ? fy : 1.f - fy;
#pragma unroll
    for (int dx = 0; dx < 2; ++dx) {
      const int xi = x0 + dx;
      const float wx = dx ? fx : 1.f - fx;
      if ((unsigned)xi < 200u && (unsigned)yi < 56u) {
        const _Float16* bp = depth + ((size_t)n * 11200 + yi * 200 + xi) * 112;
        float v0 = zv0 ? (float)bp[z0] : 0.f;
        float v1 = zv1 ? (float)bp[z0 + 1] : 0.f;
        acc += (wx * wy) * (wz0 * v0 + wz1 * v1);
      }
    }
  }
  out[i] = acc;
}

// ---------------------------------------------------------------- launch
extern "C" void kernel_launch(void* const* d_in, const int* in_sizes, int n_in,
                              void* d_out, int out_size, void* d_ws, size_t ws_size,
                              hipStream_t stream) {
  (void)in_sizes; (void)n_in; (void)out_size; (void)ws_size;
  const float* img = (const float*)d_in[0];
  const float* sps = (const float*)d_in[1];
  const float* grids = (const float*)d_in[2];
  const float* rc_w = (const float*)d_in[3];
  const float* rc_b = (const float*)d_in[4];
  const float* rc_s = (const float*)d_in[5];
  const float* rc_t = (const float*)d_in[6];
  const float* fc1_w = (const float*)d_in[7];
  const float* fc1_b = (const float*)d_in[8];
  const float* fc2_w = (const float*)d_in[9];
  const float* fc2_b = (const float*)d_in[10];
  const float* se_rw = (const float*)d_in[11];
  const float* se_rb = (const float*)d_in[12];
  const float* se_ew = (const float*)d_in[13];
  const float* se_eb = (const float*)d_in[14];
  const float* bb_w1 = (const float*)d_in[15];
  const float* bb_s1 = (const float*)d_in[16];
  const float* bb_t1 = (const float*)d_in[17];
  const float* bb_w2 = (const float*)d_in[18];
  const float* bb_s2 = (const float*)d_in[19];
  const float* bb_t2 = (const float*)d_in[20];
  const float* dp_w = (const float*)d_in[21];
  const float* dp_b = (const float*)d_in[22];
  float* outp = (float*)d_out;

  char* ws = (char*)d_ws;
  _Float16* act16 = (_Float16*)(ws + 0);
  _Float16* depth16 = (_Float16*)(ws + 0);  // reuses act16 slot (act16 dead post rc-conv)
  _Float16* xa = (_Float16*)(ws + 23068672);
  _Float16* xb = (_Float16*)(ws + 23068672 + 11534336);
  _Float16* yb = (_Float16*)(ws + 23068672 + 2 * 11534336);
  _Float16* wrc = (_Float16*)(ws + 57671680);           // 589,824 B
  _Float16* wdp = (_Float16*)(ws + 57671680 + 589824);  // 28,672 B
  _Float16* wbb = (_Float16*)(ws + 58327040);           // 1,769,472 B
  float* sig = (float*)(ws + 58327040 + 1769472);       // 2,048 B

  prep_kernel<<<dim3(808), 256, 0, stream>>>(
      rc_w, bb_w1, bb_w2, dp_w, img, sps, fc1_w, fc1_b, fc2_w, fc2_b, se_rw, se_rb,
      se_ew, se_eb, wrc, wbb, wdp, act16, sig);

  dim3 cgrid(7, 7, 8);  // 8h x 32w x 64cout, z = n*2 + cg, 392 blocks
  conv3x3_kernel<256, 0><<<cgrid, 256, 0, stream>>>(act16, wrc, nullptr, rc_b, rc_s,
                                                    rc_t, sig, xa);
  _Float16* xcur = xa;
  _Float16* xnxt = xb;
  for (int i = 0; i < 3; ++i) {
    conv3x3_kernel<128, 1><<<cgrid, 256, 0, stream>>>(
        xcur, wbb + (size_t)(2 * i) * 147456, nullptr, nullptr, bb_s1 + i * 128,
        bb_t1 + i * 128, nullptr, yb);
    conv3x3_kernel<128, 2><<<cgrid, 256, 0, stream>>>(
        yb, wbb + (size_t)(2 * i + 1) * 147456, xcur, nullptr, bb_s2 + i * 128,
        bb_t2 + i * 128, nullptr, xnxt);
    _Float16* t = xcur;
    xcur = xnxt;
    xnxt = t;
  }

  depth_proj_softmax_kernel<<<dim3(700), 256, 0, stream>>>(xcur, wdp, dp_b, depth16);
  gridsample_kernel<<<dim3(4096), 256, 0, stream>>>(grids, depth16, outp);
}